// Round 5
// baseline (1094.380 us; speedup 1.0000x reference)
//
#include <hip/hip_runtime.h>

// SimpleHGAT: fused GAT layer. Bucketed design (no fine CSR):
//  K0  zero_pad:     zero 782 padded bucket counters
//  K1  fold_kernel:  qv/kv/ev [64][4] folded projection·attention vectors
//  K2  node_proj:    hn = Xn@Wn [N,64], wq/wk [N,4]
//  K3  bhist:        bucket counts (bucket = dst>>7, counters padded 1/line)
//  K4  bscan:        1-block exclusive scan of 782 buckets -> bstart, bcur
//  K5  edge_scatter: stream xe, ex=exp(leaky(wk[src]+wq[dst]+xe@ev)),
//                    scatter {src,dst}+ex4 to bucket slot (sequential per
//                    bucket -> ~782-line active write set, L2-friendly)
//  K6  bucket_aggregate: block per bucket; acc[128][64]+den[128][4] in LDS;
//                    per edge: wave gathers hn[src] (256B, L3-resident),
//                    LDS atomicAdd; epilogue out = acc/den + bias + residual

#define NPB 128        // nodes per bucket (power of two)
#define NPB_SHIFT 7
#define PAD 32         // ints per counter -> one counter per 128B line

__global__ __launch_bounds__(1024) void zero_pad(int* __restrict__ p, int n) {
  int i = blockIdx.x * 1024 + threadIdx.x;
  if (i < n) p[i] = 0;
}

__global__ __launch_bounds__(256) void fold_kernel(
    const float* __restrict__ Wn, const float* __restrict__ We,
    const float* __restrict__ aq, const float* __restrict__ ak,
    const float* __restrict__ ae,
    float* __restrict__ qv, float* __restrict__ kv, float* __restrict__ ev) {
  int t = threadIdx.x;           // 256 threads: t = j*4 + h
  int j = t >> 2, h = t & 3;
  float sq = 0.f, sk = 0.f, se = 0.f;
#pragma unroll
  for (int d = 0; d < 16; d++) {
    float wn = Wn[j * 64 + h * 16 + d];
    float we = We[j * 64 + h * 16 + d];
    sq += wn * aq[h * 16 + d];
    sk += wn * ak[h * 16 + d];
    se += we * ae[h * 16 + d];
  }
  qv[t] = sq;
  kv[t] = sk;
  ev[t] = se;
}

__global__ __launch_bounds__(256) void node_proj(
    const float* __restrict__ xin, const float* __restrict__ W,
    const float* __restrict__ aq, const float* __restrict__ ak,
    float* __restrict__ hn, float* __restrict__ wq, float* __restrict__ wk,
    int n) {
  int node = blockIdx.x * blockDim.x + threadIdx.x;
  if (node >= n) return;
  const float4* xr = (const float4*)(xin + (size_t)node * 64);
  float x[64];
#pragma unroll
  for (int i = 0; i < 16; i++) {
    float4 v = xr[i];
    x[4 * i] = v.x; x[4 * i + 1] = v.y; x[4 * i + 2] = v.z; x[4 * i + 3] = v.w;
  }
  float q[4] = {0, 0, 0, 0}, kk[4] = {0, 0, 0, 0};
  float4* ho = (float4*)(hn + (size_t)node * 64);
  for (int c4 = 0; c4 < 16; c4++) {   // output column group (uniform across lanes)
    float a0 = 0, a1 = 0, a2 = 0, a3 = 0;
#pragma unroll
    for (int j = 0; j < 64; j++) {
      const float4 wv = *(const float4*)(W + j * 64 + c4 * 4);  // uniform -> s_load
      a0 += x[j] * wv.x; a1 += x[j] * wv.y; a2 += x[j] * wv.z; a3 += x[j] * wv.w;
    }
    float4 aqv = *(const float4*)(aq + c4 * 4);
    float4 akv = *(const float4*)(ak + c4 * 4);
    int h = c4 >> 2;
    q[h]  += a0 * aqv.x + a1 * aqv.y + a2 * aqv.z + a3 * aqv.w;
    kk[h] += a0 * akv.x + a1 * akv.y + a2 * akv.z + a3 * akv.w;
    float4 o; o.x = a0; o.y = a1; o.z = a2; o.w = a3;
    ho[c4] = o;
  }
  *(float4*)(wq + (size_t)node * 4) = make_float4(q[0], q[1], q[2], q[3]);
  *(float4*)(wk + (size_t)node * 4) = make_float4(kk[0], kk[1], kk[2], kk[3]);
}

__global__ __launch_bounds__(256) void bhist(
    const int* __restrict__ dst, int* __restrict__ bcount, int e) {
  int i = blockIdx.x * blockDim.x + threadIdx.x;
  if (i < e) atomicAdd(&bcount[(dst[i] >> NPB_SHIFT) * PAD], 1);
}

// single block, 1024 threads; B <= 1024 buckets
__global__ __launch_bounds__(1024) void bscan(
    const int* __restrict__ bcount, int* __restrict__ bstart,
    int* __restrict__ bcur, int B, int total) {
  __shared__ int wsum[16];
  int t = threadIdx.x;
  int v = (t < B) ? bcount[t * PAD] : 0;
  int x = v;
#pragma unroll
  for (int o = 1; o < 64; o <<= 1) {
    int y = __shfl_up(x, o, 64);
    if ((t & 63) >= o) x += y;
  }
  int wid = t >> 6;
  if ((t & 63) == 63) wsum[wid] = x;
  __syncthreads();
  if (t < 16) {
    int s = wsum[t];
#pragma unroll
    for (int o = 1; o < 16; o <<= 1) {
      int y = __shfl_up(s, o, 16);
      if (t >= o) s += y;
    }
    wsum[t] = s;
  }
  __syncthreads();
  int base = (wid > 0) ? wsum[wid - 1] : 0;
  int incl = base + x;
  int excl = incl - v;
  if (t < B) {
    bstart[t] = excl;
    bcur[t * PAD] = excl;
  }
  if (t == B - 1) bstart[B] = total;
}

__global__ __launch_bounds__(256) void edge_scatter(
    const float* __restrict__ xe, const int* __restrict__ src,
    const int* __restrict__ dst, const float* __restrict__ ev,
    const float* __restrict__ wq, const float* __restrict__ wk,
    int* __restrict__ bcur, int2* __restrict__ binned_sd,
    float4* __restrict__ binned_ex, int E) {
  int e = blockIdx.x * blockDim.x + threadIdx.x;
  if (e >= E) return;
  const float4* row = (const float4*)(xe + (size_t)e * 64);
  float w0 = 0, w1 = 0, w2 = 0, w3 = 0;
#pragma unroll
  for (int j4 = 0; j4 < 16; j4++) {
    float4 xv = row[j4];
    const float4 e0 = *(const float4*)(ev + (j4 * 4 + 0) * 4);  // uniform
    const float4 e1 = *(const float4*)(ev + (j4 * 4 + 1) * 4);
    const float4 e2 = *(const float4*)(ev + (j4 * 4 + 2) * 4);
    const float4 e3 = *(const float4*)(ev + (j4 * 4 + 3) * 4);
    w0 += xv.x * e0.x + xv.y * e1.x + xv.z * e2.x + xv.w * e3.x;
    w1 += xv.x * e0.y + xv.y * e1.y + xv.z * e2.y + xv.w * e3.y;
    w2 += xv.x * e0.z + xv.y * e1.z + xv.z * e2.z + xv.w * e3.z;
    w3 += xv.x * e0.w + xv.y * e1.w + xv.z * e2.w + xv.w * e3.w;
  }
  int s = src[e], d = dst[e];
  float4 kv4 = *(const float4*)(wk + (size_t)s * 4);
  float4 qv4 = *(const float4*)(wq + (size_t)d * 4);
  float l0 = kv4.x + qv4.x + w0;
  float l1 = kv4.y + qv4.y + w1;
  float l2 = kv4.z + qv4.z + w2;
  float l3 = kv4.w + qv4.w + w3;
  l0 = l0 > 0.f ? l0 : 0.01f * l0;
  l1 = l1 > 0.f ? l1 : 0.01f * l1;
  l2 = l2 > 0.f ? l2 : 0.01f * l2;
  l3 = l3 > 0.f ? l3 : 0.01f * l3;
  // shift-free softmax numerator: |logit| <~ 20 so exp() is safe in f32
  float4 exv = make_float4(__expf(l0), __expf(l1), __expf(l2), __expf(l3));
  int b = d >> NPB_SHIFT;
  int pos = atomicAdd(&bcur[b * PAD], 1);   // bucket-sequential -> L2-warm lines
  binned_sd[pos] = make_int2(s, d);
  binned_ex[pos] = exv;
}

__global__ __launch_bounds__(256) void bucket_aggregate(
    const int* __restrict__ bstart, const int2* __restrict__ binned_sd,
    const float4* __restrict__ binned_ex, const float* __restrict__ hn,
    const float* __restrict__ xin, const float* __restrict__ bias,
    float* __restrict__ out, int n) {
  __shared__ float accS[NPB][64];
  __shared__ float denS[NPB][4];
  int b = blockIdx.x;
  int node0 = b << NPB_SHIFT;
  int nnode = min(NPB, n - node0);
  int t = threadIdx.x, lane = t & 63, wid = t >> 6;
  int h = lane >> 4;
  for (int i = t; i < NPB * 64; i += 256) ((float*)accS)[i] = 0.f;
  for (int i = t; i < NPB * 4; i += 256) ((float*)denS)[i] = 0.f;
  __syncthreads();
  int s0 = bstart[b], s1 = bstart[b + 1];
  // each wave takes a contiguous chunk, unroll x4 for MLP on the hn gather
  int cnt = s1 - s0;
  int chunk = (cnt + 3) >> 2;
  int ws = s0 + wid * chunk;
  int we = min(ws + chunk, s1);
  int i = ws;
  for (; i + 4 <= we; i += 4) {
    int2 sd0 = binned_sd[i + 0], sd1 = binned_sd[i + 1];
    int2 sd2 = binned_sd[i + 2], sd3 = binned_sd[i + 3];
    float4 x0 = binned_ex[i + 0], x1 = binned_ex[i + 1];
    float4 x2 = binned_ex[i + 2], x3 = binned_ex[i + 3];
    float v0 = hn[(size_t)sd0.x * 64 + lane];
    float v1 = hn[(size_t)sd1.x * 64 + lane];
    float v2 = hn[(size_t)sd2.x * 64 + lane];
    float v3 = hn[(size_t)sd3.x * 64 + lane];
    float e0 = (h == 0) ? x0.x : (h == 1) ? x0.y : (h == 2) ? x0.z : x0.w;
    float e1 = (h == 0) ? x1.x : (h == 1) ? x1.y : (h == 2) ? x1.z : x1.w;
    float e2 = (h == 0) ? x2.x : (h == 1) ? x2.y : (h == 2) ? x2.z : x2.w;
    float e3 = (h == 0) ? x3.x : (h == 1) ? x3.y : (h == 2) ? x3.z : x3.w;
    atomicAdd(&accS[sd0.y - node0][lane], e0 * v0);
    atomicAdd(&accS[sd1.y - node0][lane], e1 * v1);
    atomicAdd(&accS[sd2.y - node0][lane], e2 * v2);
    atomicAdd(&accS[sd3.y - node0][lane], e3 * v3);
    if ((lane & 15) == 0) {
      atomicAdd(&denS[sd0.y - node0][h], e0);
      atomicAdd(&denS[sd1.y - node0][h], e1);
      atomicAdd(&denS[sd2.y - node0][h], e2);
      atomicAdd(&denS[sd3.y - node0][h], e3);
    }
  }
  for (; i < we; i++) {
    int2 sd = binned_sd[i];
    float4 xv = binned_ex[i];
    float ex = (h == 0) ? xv.x : (h == 1) ? xv.y : (h == 2) ? xv.z : xv.w;
    float hv = hn[(size_t)sd.x * 64 + lane];
    atomicAdd(&accS[sd.y - node0][lane], ex * hv);
    if ((lane & 15) == 0) atomicAdd(&denS[sd.y - node0][h], ex);
  }
  __syncthreads();
  for (int ld = wid; ld < nnode; ld += 4) {
    int node = node0 + ld;
    float den = denS[ld][h];
    float acc = accS[ld][lane];
    float r = (den > 0.f) ? acc / den : 0.f;
    out[(size_t)node * 64 + lane] = r + bias[lane] + xin[(size_t)node * 64 + lane];
  }
}

extern "C" void kernel_launch(void* const* d_in, const int* in_sizes, int n_in,
                              void* d_out, int out_size, void* d_ws, size_t ws_size,
                              hipStream_t stream) {
  const float* xn  = (const float*)d_in[0];
  const float* xe  = (const float*)d_in[1];
  const int*   src = (const int*)d_in[2];
  const int*   dst = (const int*)d_in[3];
  const float* Wn  = (const float*)d_in[4];
  const float* We  = (const float*)d_in[5];
  const float* aq  = (const float*)d_in[6];
  const float* ak  = (const float*)d_in[7];
  const float* ae  = (const float*)d_in[8];
  const float* bias = (const float*)d_in[9];
  float* out = (float*)d_out;

  const int n = in_sizes[0] / 64;   // 100000
  const int E = in_sizes[2];        // 1600000
  const int B = (n + NPB - 1) >> NPB_SHIFT;  // 782 buckets (<=1024 for bscan)
  if (B > 1024) return;

  // workspace carve (256B aligned)
  size_t off = 0;
  auto carve = [&](size_t bytes) {
    size_t p = off;
    off = (off + bytes + 255) & ~(size_t)255;
    return p;
  };
  char* ws = (char*)d_ws;
  size_t o_hn    = carve((size_t)n * 64 * 4);
  size_t o_wq    = carve((size_t)n * 4 * 4);
  size_t o_wk    = carve((size_t)n * 4 * 4);
  size_t o_qv    = carve(256 * 4);
  size_t o_kv    = carve(256 * 4);
  size_t o_ev    = carve(256 * 4);
  size_t o_bcnt  = carve((size_t)B * PAD * 4);
  size_t o_bcur  = carve((size_t)B * PAD * 4);
  size_t o_bst   = carve((size_t)(B + 1) * 4);
  size_t o_bsd   = carve((size_t)E * 8);
  size_t o_bex   = carve((size_t)E * 16);
  if (off > ws_size) return;  // insufficient workspace -> fail loudly

  float* hn      = (float*)(ws + o_hn);
  float* wq      = (float*)(ws + o_wq);
  float* wk      = (float*)(ws + o_wk);
  float* qv      = (float*)(ws + o_qv);
  float* kv      = (float*)(ws + o_kv);
  float* ev      = (float*)(ws + o_ev);
  int*   bcount  = (int*)(ws + o_bcnt);
  int*   bcur    = (int*)(ws + o_bcur);
  int*   bstart  = (int*)(ws + o_bst);
  int2*  binned_sd = (int2*)(ws + o_bsd);
  float4* binned_ex = (float4*)(ws + o_bex);

  zero_pad<<<(B * PAD + 1023) / 1024, 1024, 0, stream>>>(bcount, B * PAD);
  fold_kernel<<<1, 256, 0, stream>>>(Wn, We, aq, ak, ae, qv, kv, ev);
  node_proj<<<(n + 255) / 256, 256, 0, stream>>>(xn, Wn, aq, ak, hn, wq, wk, n);
  bhist<<<(E + 255) / 256, 256, 0, stream>>>(dst, bcount, E);
  bscan<<<1, 1024, 0, stream>>>(bcount, bstart, bcur, B, E);
  edge_scatter<<<(E + 255) / 256, 256, 0, stream>>>(
      xe, src, dst, ev, wq, wk, bcur, binned_sd, binned_ex, E);
  bucket_aggregate<<<B, 256, 0, stream>>>(
      bstart, binned_sd, binned_ex, hn, xn, bias, out, n);
}

// Round 6
// 919.121 us; speedup vs baseline: 1.1907x; 1.1907x over previous
//
#include <hip/hip_runtime.h>

// SimpleHGAT: fused GAT layer. Bucketed design (no fine CSR), NPB=16:
//  K0  zero_pad:     zero padded bucket counters
//  K1  fold_kernel:  qv/kv/ev [64][4] folded projection·attention vectors
//  K2  node_proj:    hn = Xn@Wn [N,64], wq/wk [N,4]
//  K3  bhist:        bucket counts (bucket = dst>>4, counters padded 1/line)
//  K4  bscan:        1-block looped exclusive scan of B buckets -> bstart, bcur
//  K5  edge_scatter: stream xe, ex=exp(leaky(wk[src]+wq[dst]+xe@ev)),
//                    scatter {src,dst}+ex4 to bucket slot (bucket-sequential
//                    -> ~6250-line active write set, L2-warm)
//  K6  bucket_aggregate: block per bucket (6250 blocks -> latency hidden);
//                    acc[16][64]+den[16][4] in LDS (4.25KB); per edge: wave
//                    gathers hn[src] (256B coalesced), ds_add; epilogue
//                    out = acc/den + bias + residual

#define NPB 16         // nodes per bucket (power of two)
#define NPB_SHIFT 4
#define PAD 32         // ints per counter -> one counter per 128B line

__global__ __launch_bounds__(1024) void zero_pad(int* __restrict__ p, int n) {
  int i = blockIdx.x * 1024 + threadIdx.x;
  if (i < n) p[i] = 0;
}

__global__ __launch_bounds__(256) void fold_kernel(
    const float* __restrict__ Wn, const float* __restrict__ We,
    const float* __restrict__ aq, const float* __restrict__ ak,
    const float* __restrict__ ae,
    float* __restrict__ qv, float* __restrict__ kv, float* __restrict__ ev) {
  int t = threadIdx.x;           // 256 threads: t = j*4 + h
  int j = t >> 2, h = t & 3;
  float sq = 0.f, sk = 0.f, se = 0.f;
#pragma unroll
  for (int d = 0; d < 16; d++) {
    float wn = Wn[j * 64 + h * 16 + d];
    float we = We[j * 64 + h * 16 + d];
    sq += wn * aq[h * 16 + d];
    sk += wn * ak[h * 16 + d];
    se += we * ae[h * 16 + d];
  }
  qv[t] = sq;
  kv[t] = sk;
  ev[t] = se;
}

__global__ __launch_bounds__(256) void node_proj(
    const float* __restrict__ xin, const float* __restrict__ W,
    const float* __restrict__ aq, const float* __restrict__ ak,
    float* __restrict__ hn, float* __restrict__ wq, float* __restrict__ wk,
    int n) {
  int node = blockIdx.x * blockDim.x + threadIdx.x;
  if (node >= n) return;
  const float4* xr = (const float4*)(xin + (size_t)node * 64);
  float x[64];
#pragma unroll
  for (int i = 0; i < 16; i++) {
    float4 v = xr[i];
    x[4 * i] = v.x; x[4 * i + 1] = v.y; x[4 * i + 2] = v.z; x[4 * i + 3] = v.w;
  }
  float q[4] = {0, 0, 0, 0}, kk[4] = {0, 0, 0, 0};
  float4* ho = (float4*)(hn + (size_t)node * 64);
  for (int c4 = 0; c4 < 16; c4++) {   // output column group (uniform across lanes)
    float a0 = 0, a1 = 0, a2 = 0, a3 = 0;
#pragma unroll
    for (int j = 0; j < 64; j++) {
      const float4 wv = *(const float4*)(W + j * 64 + c4 * 4);  // uniform -> s_load
      a0 += x[j] * wv.x; a1 += x[j] * wv.y; a2 += x[j] * wv.z; a3 += x[j] * wv.w;
    }
    float4 aqv = *(const float4*)(aq + c4 * 4);
    float4 akv = *(const float4*)(ak + c4 * 4);
    int h = c4 >> 2;
    q[h]  += a0 * aqv.x + a1 * aqv.y + a2 * aqv.z + a3 * aqv.w;
    kk[h] += a0 * akv.x + a1 * akv.y + a2 * akv.z + a3 * akv.w;
    float4 o; o.x = a0; o.y = a1; o.z = a2; o.w = a3;
    ho[c4] = o;
  }
  *(float4*)(wq + (size_t)node * 4) = make_float4(q[0], q[1], q[2], q[3]);
  *(float4*)(wk + (size_t)node * 4) = make_float4(kk[0], kk[1], kk[2], kk[3]);
}

__global__ __launch_bounds__(256) void bhist(
    const int* __restrict__ dst, int* __restrict__ bcount, int e) {
  int i = blockIdx.x * blockDim.x + threadIdx.x;
  if (i < e) atomicAdd(&bcount[(dst[i] >> NPB_SHIFT) * PAD], 1);
}

// single block, 1024 threads, loops over B buckets with carried prefix
__global__ __launch_bounds__(1024) void bscan(
    const int* __restrict__ bcount, int* __restrict__ bstart,
    int* __restrict__ bcur, int B, int total) {
  __shared__ int wsum[16];
  __shared__ int carry;
  if (threadIdx.x == 0) carry = 0;
  __syncthreads();
  for (int base = 0; base < B; base += 1024) {
    int t = base + threadIdx.x;
    int v = (t < B) ? bcount[t * PAD] : 0;
    int x = v;
#pragma unroll
    for (int o = 1; o < 64; o <<= 1) {
      int y = __shfl_up(x, o, 64);
      if ((threadIdx.x & 63) >= o) x += y;
    }
    int wid = threadIdx.x >> 6;
    if ((threadIdx.x & 63) == 63) wsum[wid] = x;
    __syncthreads();
    if (threadIdx.x < 16) {
      int s = wsum[threadIdx.x];
#pragma unroll
      for (int o = 1; o < 16; o <<= 1) {
        int y = __shfl_up(s, o, 16);
        if ((int)threadIdx.x >= o) s += y;
      }
      wsum[threadIdx.x] = s;
    }
    __syncthreads();
    int wbase = (wid > 0) ? wsum[wid - 1] : 0;
    int incl = wbase + x;
    int c = carry;
    if (t < B) {
      int excl = c + incl - v;
      bstart[t] = excl;
      bcur[t * PAD] = excl;
    }
    __syncthreads();                       // all reads of carry/wsum done
    if (threadIdx.x == 1023) carry = c + incl;   // += block total
    __syncthreads();
  }
  if (threadIdx.x == 0) bstart[B] = total;
}

__global__ __launch_bounds__(256) void edge_scatter(
    const float* __restrict__ xe, const int* __restrict__ src,
    const int* __restrict__ dst, const float* __restrict__ ev,
    const float* __restrict__ wq, const float* __restrict__ wk,
    int* __restrict__ bcur, int2* __restrict__ binned_sd,
    float4* __restrict__ binned_ex, int E) {
  int e = blockIdx.x * blockDim.x + threadIdx.x;
  if (e >= E) return;
  const float4* row = (const float4*)(xe + (size_t)e * 64);
  float w0 = 0, w1 = 0, w2 = 0, w3 = 0;
#pragma unroll
  for (int j4 = 0; j4 < 16; j4++) {
    float4 xv = row[j4];
    const float4 e0 = *(const float4*)(ev + (j4 * 4 + 0) * 4);  // uniform
    const float4 e1 = *(const float4*)(ev + (j4 * 4 + 1) * 4);
    const float4 e2 = *(const float4*)(ev + (j4 * 4 + 2) * 4);
    const float4 e3 = *(const float4*)(ev + (j4 * 4 + 3) * 4);
    w0 += xv.x * e0.x + xv.y * e1.x + xv.z * e2.x + xv.w * e3.x;
    w1 += xv.x * e0.y + xv.y * e1.y + xv.z * e2.y + xv.w * e3.y;
    w2 += xv.x * e0.z + xv.y * e1.z + xv.z * e2.z + xv.w * e3.z;
    w3 += xv.x * e0.w + xv.y * e1.w + xv.z * e2.w + xv.w * e3.w;
  }
  int s = src[e], d = dst[e];
  float4 kv4 = *(const float4*)(wk + (size_t)s * 4);
  float4 qv4 = *(const float4*)(wq + (size_t)d * 4);
  float l0 = kv4.x + qv4.x + w0;
  float l1 = kv4.y + qv4.y + w1;
  float l2 = kv4.z + qv4.z + w2;
  float l3 = kv4.w + qv4.w + w3;
  l0 = l0 > 0.f ? l0 : 0.01f * l0;
  l1 = l1 > 0.f ? l1 : 0.01f * l1;
  l2 = l2 > 0.f ? l2 : 0.01f * l2;
  l3 = l3 > 0.f ? l3 : 0.01f * l3;
  // shift-free softmax numerator: |logit| <~ 20 so exp() is safe in f32
  float4 exv = make_float4(__expf(l0), __expf(l1), __expf(l2), __expf(l3));
  int b = d >> NPB_SHIFT;
  int pos = atomicAdd(&bcur[b * PAD], 1);   // bucket-sequential -> L2-warm lines
  binned_sd[pos] = make_int2(s, d);
  binned_ex[pos] = exv;
}

__global__ __launch_bounds__(256) void bucket_aggregate(
    const int* __restrict__ bstart, const int2* __restrict__ binned_sd,
    const float4* __restrict__ binned_ex, const float* __restrict__ hn,
    const float* __restrict__ xin, const float* __restrict__ bias,
    float* __restrict__ out, int n) {
  __shared__ float accS[NPB][64];
  __shared__ float denS[NPB][4];
  int b = blockIdx.x;
  int node0 = b << NPB_SHIFT;
  int nnode = min(NPB, n - node0);
  int t = threadIdx.x, lane = t & 63, wid = t >> 6;
  int h = lane >> 4;
  for (int i = t; i < NPB * 64; i += 256) ((float*)accS)[i] = 0.f;
  for (int i = t; i < NPB * 4; i += 256) ((float*)denS)[i] = 0.f;
  __syncthreads();
  int s0 = bstart[b], s1 = bstart[b + 1];
  // each wave takes a contiguous chunk, unroll x4 for MLP on the hn gather
  int cnt = s1 - s0;
  int chunk = (cnt + 3) >> 2;
  int ws = s0 + wid * chunk;
  int we = min(ws + chunk, s1);
  int i = ws;
  for (; i + 4 <= we; i += 4) {
    int2 sd0 = binned_sd[i + 0], sd1 = binned_sd[i + 1];
    int2 sd2 = binned_sd[i + 2], sd3 = binned_sd[i + 3];
    float4 x0 = binned_ex[i + 0], x1 = binned_ex[i + 1];
    float4 x2 = binned_ex[i + 2], x3 = binned_ex[i + 3];
    float v0 = hn[(size_t)sd0.x * 64 + lane];
    float v1 = hn[(size_t)sd1.x * 64 + lane];
    float v2 = hn[(size_t)sd2.x * 64 + lane];
    float v3 = hn[(size_t)sd3.x * 64 + lane];
    float e0 = (h == 0) ? x0.x : (h == 1) ? x0.y : (h == 2) ? x0.z : x0.w;
    float e1 = (h == 0) ? x1.x : (h == 1) ? x1.y : (h == 2) ? x1.z : x1.w;
    float e2 = (h == 0) ? x2.x : (h == 1) ? x2.y : (h == 2) ? x2.z : x2.w;
    float e3 = (h == 0) ? x3.x : (h == 1) ? x3.y : (h == 2) ? x3.z : x3.w;
    atomicAdd(&accS[sd0.y - node0][lane], e0 * v0);
    atomicAdd(&accS[sd1.y - node0][lane], e1 * v1);
    atomicAdd(&accS[sd2.y - node0][lane], e2 * v2);
    atomicAdd(&accS[sd3.y - node0][lane], e3 * v3);
    if ((lane & 15) == 0) {
      atomicAdd(&denS[sd0.y - node0][h], e0);
      atomicAdd(&denS[sd1.y - node0][h], e1);
      atomicAdd(&denS[sd2.y - node0][h], e2);
      atomicAdd(&denS[sd3.y - node0][h], e3);
    }
  }
  for (; i < we; i++) {
    int2 sd = binned_sd[i];
    float4 xv = binned_ex[i];
    float ex = (h == 0) ? xv.x : (h == 1) ? xv.y : (h == 2) ? xv.z : xv.w;
    float hv = hn[(size_t)sd.x * 64 + lane];
    atomicAdd(&accS[sd.y - node0][lane], ex * hv);
    if ((lane & 15) == 0) atomicAdd(&denS[sd.y - node0][h], ex);
  }
  __syncthreads();
  for (int ld = wid; ld < nnode; ld += 4) {
    int node = node0 + ld;
    float den = denS[ld][h];
    float acc = accS[ld][lane];
    float r = (den > 0.f) ? acc / den : 0.f;
    out[(size_t)node * 64 + lane] = r + bias[lane] + xin[(size_t)node * 64 + lane];
  }
}

extern "C" void kernel_launch(void* const* d_in, const int* in_sizes, int n_in,
                              void* d_out, int out_size, void* d_ws, size_t ws_size,
                              hipStream_t stream) {
  const float* xn  = (const float*)d_in[0];
  const float* xe  = (const float*)d_in[1];
  const int*   src = (const int*)d_in[2];
  const int*   dst = (const int*)d_in[3];
  const float* Wn  = (const float*)d_in[4];
  const float* We  = (const float*)d_in[5];
  const float* aq  = (const float*)d_in[6];
  const float* ak  = (const float*)d_in[7];
  const float* ae  = (const float*)d_in[8];
  const float* bias = (const float*)d_in[9];
  float* out = (float*)d_out;

  const int n = in_sizes[0] / 64;   // 100000
  const int E = in_sizes[2];        // 1600000
  const int B = (n + NPB - 1) >> NPB_SHIFT;  // 6250 buckets

  // workspace carve (256B aligned)
  size_t off = 0;
  auto carve = [&](size_t bytes) {
    size_t p = off;
    off = (off + bytes + 255) & ~(size_t)255;
    return p;
  };
  char* ws = (char*)d_ws;
  size_t o_hn    = carve((size_t)n * 64 * 4);
  size_t o_wq    = carve((size_t)n * 4 * 4);
  size_t o_wk    = carve((size_t)n * 4 * 4);
  size_t o_qv    = carve(256 * 4);
  size_t o_kv    = carve(256 * 4);
  size_t o_ev    = carve(256 * 4);
  size_t o_bcnt  = carve((size_t)B * PAD * 4);
  size_t o_bcur  = carve((size_t)B * PAD * 4);
  size_t o_bst   = carve((size_t)(B + 1) * 4);
  size_t o_bsd   = carve((size_t)E * 8);
  size_t o_bex   = carve((size_t)E * 16);
  if (off > ws_size) return;  // insufficient workspace -> fail loudly

  float* hn      = (float*)(ws + o_hn);
  float* wq      = (float*)(ws + o_wq);
  float* wk      = (float*)(ws + o_wk);
  float* qv      = (float*)(ws + o_qv);
  float* kv      = (float*)(ws + o_kv);
  float* ev      = (float*)(ws + o_ev);
  int*   bcount  = (int*)(ws + o_bcnt);
  int*   bcur    = (int*)(ws + o_bcur);
  int*   bstart  = (int*)(ws + o_bst);
  int2*  binned_sd = (int2*)(ws + o_bsd);
  float4* binned_ex = (float4*)(ws + o_bex);

  zero_pad<<<(B * PAD + 1023) / 1024, 1024, 0, stream>>>(bcount, B * PAD);
  fold_kernel<<<1, 256, 0, stream>>>(Wn, We, aq, ak, ae, qv, kv, ev);
  node_proj<<<(n + 255) / 256, 256, 0, stream>>>(xn, Wn, aq, ak, hn, wq, wk, n);
  bhist<<<(E + 255) / 256, 256, 0, stream>>>(dst, bcount, E);
  bscan<<<1, 1024, 0, stream>>>(bcount, bstart, bcur, B, E);
  edge_scatter<<<(E + 255) / 256, 256, 0, stream>>>(
      xe, src, dst, ev, wq, wk, bcur, binned_sd, binned_ex, E);
  bucket_aggregate<<<B, 256, 0, stream>>>(
      bstart, binned_sd, binned_ex, hn, xn, bias, out, n);
}

// Round 7
// 546.043 us; speedup vs baseline: 2.0042x; 1.6832x over previous
//
#include <hip/hip_runtime.h>

// SimpleHGAT: fused GAT layer. Bucketed design, NPB=16:
//  K0  zero_pad:     zero padded bucket counters
//  K1  fold_kernel:  qv/kv/ev [64][4] folded projection·attention vectors
//  K2  node_proj:    hn = Xn@Wn [N,64], wq/wk [N,4]
//  K3  bhist:        bucket counts (bucket = dst>>4, counters padded 1/line)
//  K4  bscan:        1-block looped exclusive scan of B buckets -> bstart, bcur
//  K5  edge_scatter: NONTEMPORAL stream of xe/src/dst (read-once data must not
//                    evict the L2-resident scatter lines), ex=exp(leaky(...)),
//                    scatter {src,dst}+ex4 to bucket slot
//  K6  bucket_aggregate: block per bucket; two-pass LDS binning by local dst
//                    (int cursors only), then wave-per-node REGISTER accumulate
//                    (no fp atomics); epilogue out = acc/den + bias + residual

#define NPB 16         // nodes per bucket (power of two)
#define NPB_SHIFT 4
#define PAD 32         // ints per counter -> one counter per 128B line
#define CAP 2048       // max edges binned in LDS; larger buckets take fallback

typedef float f32x4 __attribute__((ext_vector_type(4)));

__global__ __launch_bounds__(1024) void zero_pad(int* __restrict__ p, int n) {
  int i = blockIdx.x * 1024 + threadIdx.x;
  if (i < n) p[i] = 0;
}

__global__ __launch_bounds__(256) void fold_kernel(
    const float* __restrict__ Wn, const float* __restrict__ We,
    const float* __restrict__ aq, const float* __restrict__ ak,
    const float* __restrict__ ae,
    float* __restrict__ qv, float* __restrict__ kv, float* __restrict__ ev) {
  int t = threadIdx.x;           // 256 threads: t = j*4 + h
  int j = t >> 2, h = t & 3;
  float sq = 0.f, sk = 0.f, se = 0.f;
#pragma unroll
  for (int d = 0; d < 16; d++) {
    float wn = Wn[j * 64 + h * 16 + d];
    float we = We[j * 64 + h * 16 + d];
    sq += wn * aq[h * 16 + d];
    sk += wn * ak[h * 16 + d];
    se += we * ae[h * 16 + d];
  }
  qv[t] = sq;
  kv[t] = sk;
  ev[t] = se;
}

__global__ __launch_bounds__(256) void node_proj(
    const float* __restrict__ xin, const float* __restrict__ W,
    const float* __restrict__ aq, const float* __restrict__ ak,
    float* __restrict__ hn, float* __restrict__ wq, float* __restrict__ wk,
    int n) {
  int node = blockIdx.x * blockDim.x + threadIdx.x;
  if (node >= n) return;
  const float4* xr = (const float4*)(xin + (size_t)node * 64);
  float x[64];
#pragma unroll
  for (int i = 0; i < 16; i++) {
    float4 v = xr[i];
    x[4 * i] = v.x; x[4 * i + 1] = v.y; x[4 * i + 2] = v.z; x[4 * i + 3] = v.w;
  }
  float q[4] = {0, 0, 0, 0}, kk[4] = {0, 0, 0, 0};
  float4* ho = (float4*)(hn + (size_t)node * 64);
  for (int c4 = 0; c4 < 16; c4++) {   // output column group (uniform across lanes)
    float a0 = 0, a1 = 0, a2 = 0, a3 = 0;
#pragma unroll
    for (int j = 0; j < 64; j++) {
      const float4 wv = *(const float4*)(W + j * 64 + c4 * 4);  // uniform -> s_load
      a0 += x[j] * wv.x; a1 += x[j] * wv.y; a2 += x[j] * wv.z; a3 += x[j] * wv.w;
    }
    float4 aqv = *(const float4*)(aq + c4 * 4);
    float4 akv = *(const float4*)(ak + c4 * 4);
    int h = c4 >> 2;
    q[h]  += a0 * aqv.x + a1 * aqv.y + a2 * aqv.z + a3 * aqv.w;
    kk[h] += a0 * akv.x + a1 * akv.y + a2 * akv.z + a3 * akv.w;
    float4 o; o.x = a0; o.y = a1; o.z = a2; o.w = a3;
    ho[c4] = o;
  }
  *(float4*)(wq + (size_t)node * 4) = make_float4(q[0], q[1], q[2], q[3]);
  *(float4*)(wk + (size_t)node * 4) = make_float4(kk[0], kk[1], kk[2], kk[3]);
}

__global__ __launch_bounds__(256) void bhist(
    const int* __restrict__ dst, int* __restrict__ bcount, int e) {
  int i = blockIdx.x * blockDim.x + threadIdx.x;
  if (i < e) atomicAdd(&bcount[(dst[i] >> NPB_SHIFT) * PAD], 1);
}

// single block, 1024 threads, loops over B buckets with carried prefix
__global__ __launch_bounds__(1024) void bscan(
    const int* __restrict__ bcount, int* __restrict__ bstart,
    int* __restrict__ bcur, int B, int total) {
  __shared__ int wsum[16];
  __shared__ int carry;
  if (threadIdx.x == 0) carry = 0;
  __syncthreads();
  for (int base = 0; base < B; base += 1024) {
    int t = base + threadIdx.x;
    int v = (t < B) ? bcount[t * PAD] : 0;
    int x = v;
#pragma unroll
    for (int o = 1; o < 64; o <<= 1) {
      int y = __shfl_up(x, o, 64);
      if ((threadIdx.x & 63) >= o) x += y;
    }
    int wid = threadIdx.x >> 6;
    if ((threadIdx.x & 63) == 63) wsum[wid] = x;
    __syncthreads();
    if (threadIdx.x < 16) {
      int s = wsum[threadIdx.x];
#pragma unroll
      for (int o = 1; o < 16; o <<= 1) {
        int y = __shfl_up(s, o, 16);
        if ((int)threadIdx.x >= o) s += y;
      }
      wsum[threadIdx.x] = s;
    }
    __syncthreads();
    int wbase = (wid > 0) ? wsum[wid - 1] : 0;
    int incl = wbase + x;
    int c = carry;
    if (t < B) {
      int excl = c + incl - v;
      bstart[t] = excl;
      bcur[t * PAD] = excl;
    }
    __syncthreads();                       // all reads of carry/wsum done
    if (threadIdx.x == 1023) carry = c + incl;   // += block total
    __syncthreads();
  }
  if (threadIdx.x == 0) bstart[B] = total;
}

__global__ __launch_bounds__(256) void edge_scatter(
    const float* __restrict__ xe, const int* __restrict__ src,
    const int* __restrict__ dst, const float* __restrict__ ev,
    const float* __restrict__ wq, const float* __restrict__ wk,
    int* __restrict__ bcur, int2* __restrict__ binned_sd,
    float4* __restrict__ binned_ex, int E) {
  int e = blockIdx.x * blockDim.x + threadIdx.x;
  if (e >= E) return;
  const f32x4* row = (const f32x4*)(xe + (size_t)e * 64);
  float w0 = 0, w1 = 0, w2 = 0, w3 = 0;
#pragma unroll
  for (int j4 = 0; j4 < 16; j4++) {
    f32x4 xv = __builtin_nontemporal_load(&row[j4]);   // read-once stream: nt
    const float4 e0 = *(const float4*)(ev + (j4 * 4 + 0) * 4);  // uniform, cached
    const float4 e1 = *(const float4*)(ev + (j4 * 4 + 1) * 4);
    const float4 e2 = *(const float4*)(ev + (j4 * 4 + 2) * 4);
    const float4 e3 = *(const float4*)(ev + (j4 * 4 + 3) * 4);
    w0 += xv.x * e0.x + xv.y * e1.x + xv.z * e2.x + xv.w * e3.x;
    w1 += xv.x * e0.y + xv.y * e1.y + xv.z * e2.y + xv.w * e3.y;
    w2 += xv.x * e0.z + xv.y * e1.z + xv.z * e2.z + xv.w * e3.z;
    w3 += xv.x * e0.w + xv.y * e1.w + xv.z * e2.w + xv.w * e3.w;
  }
  int s = __builtin_nontemporal_load(&src[e]);
  int d = __builtin_nontemporal_load(&dst[e]);
  float4 kv4 = *(const float4*)(wk + (size_t)s * 4);
  float4 qv4 = *(const float4*)(wq + (size_t)d * 4);
  float l0 = kv4.x + qv4.x + w0;
  float l1 = kv4.y + qv4.y + w1;
  float l2 = kv4.z + qv4.z + w2;
  float l3 = kv4.w + qv4.w + w3;
  l0 = l0 > 0.f ? l0 : 0.01f * l0;
  l1 = l1 > 0.f ? l1 : 0.01f * l1;
  l2 = l2 > 0.f ? l2 : 0.01f * l2;
  l3 = l3 > 0.f ? l3 : 0.01f * l3;
  // shift-free softmax numerator: |logit| <~ 20 so exp() is safe in f32
  float4 exv = make_float4(__expf(l0), __expf(l1), __expf(l2), __expf(l3));
  int b = d >> NPB_SHIFT;
  int pos = atomicAdd(&bcur[b * PAD], 1);   // bucket-sequential, L2-warm lines
  binned_sd[pos] = make_int2(s, d);
  binned_ex[pos] = exv;
}

__global__ __launch_bounds__(256) void bucket_aggregate(
    const int* __restrict__ bstart, const int2* __restrict__ binned_sd,
    const float4* __restrict__ binned_ex, const float* __restrict__ hn,
    const float* __restrict__ xin, const float* __restrict__ bias,
    float* __restrict__ out, int n) {
  __shared__ int offs[NPB + 1];
  __shared__ int cur[NPB];
  __shared__ unsigned short list[CAP];
  int b = blockIdx.x;
  int node0 = b << NPB_SHIFT;
  int t = threadIdx.x, lane = t & 63, wid = t >> 6;
  int h = lane >> 4;
  int s0 = bstart[b], s1 = bstart[b + 1];
  int cnt = s1 - s0;
  const float* exf = (const float*)binned_ex;
  const int* sdi = (const int*)binned_sd;

  if (cnt <= CAP) {
    // ---- pass 1: count per local-dst ----
    if (t < NPB + 1) offs[t] = 0;
    __syncthreads();
    for (int j = t; j < cnt; j += 256)
      atomicAdd(&offs[(binned_sd[s0 + j].y & (NPB - 1)) + 1], 1);
    __syncthreads();
    if (t == 0) {
      int run = 0;
#pragma unroll
      for (int k = 0; k < NPB; k++) { run += offs[k + 1]; offs[k + 1] = run; }
    }
    __syncthreads();
    if (t < NPB) cur[t] = offs[t];
    __syncthreads();
    // ---- pass 2: scatter edge-local index into per-node list ----
    for (int j = t; j < cnt; j += 256) {
      int dl = binned_sd[s0 + j].y & (NPB - 1);
      int p = atomicAdd(&cur[dl], 1);
      list[p] = (unsigned short)j;
    }
    __syncthreads();
    // ---- wave per node, register accumulation (no fp atomics) ----
#pragma unroll
    for (int q = 0; q < 4; q++) {
      int nd = wid + 4 * q;
      int node = node0 + nd;
      if (node >= n) continue;
      int o0 = offs[nd], o1 = offs[nd + 1];
      float den0 = 0.f, den1 = 0.f, acc0 = 0.f, acc1 = 0.f;
      int i = o0;
      for (; i + 4 <= o1; i += 4) {
        int j0 = list[i + 0], j1 = list[i + 1];
        int j2 = list[i + 2], j3 = list[i + 3];
        int sv0 = sdi[(size_t)(s0 + j0) * 2];
        int sv1 = sdi[(size_t)(s0 + j1) * 2];
        int sv2 = sdi[(size_t)(s0 + j2) * 2];
        int sv3 = sdi[(size_t)(s0 + j3) * 2];
        float e0 = exf[(size_t)(s0 + j0) * 4 + h];
        float e1 = exf[(size_t)(s0 + j1) * 4 + h];
        float e2 = exf[(size_t)(s0 + j2) * 4 + h];
        float e3 = exf[(size_t)(s0 + j3) * 4 + h];
        float v0 = hn[(size_t)sv0 * 64 + lane];
        float v1 = hn[(size_t)sv1 * 64 + lane];
        float v2 = hn[(size_t)sv2 * 64 + lane];
        float v3 = hn[(size_t)sv3 * 64 + lane];
        den0 += e0 + e2; den1 += e1 + e3;
        acc0 += e0 * v0; acc1 += e1 * v1;
        acc0 += e2 * v2; acc1 += e3 * v3;
      }
      for (; i < o1; i++) {
        int j = list[i];
        int sv = sdi[(size_t)(s0 + j) * 2];
        float e = exf[(size_t)(s0 + j) * 4 + h];
        float v = hn[(size_t)sv * 64 + lane];
        den0 += e; acc0 += e * v;
      }
      float den = den0 + den1, acc = acc0 + acc1;
      float r = (o1 > o0) ? acc / den : 0.f;
      out[(size_t)node * 64 + lane] =
          r + bias[lane] + xin[(size_t)node * 64 + lane];
    }
  } else {
    // ---- fallback (bucket > CAP edges; correct for any input): scan-filter ----
#pragma unroll 1
    for (int q = 0; q < 4; q++) {
      int nd = wid + 4 * q;
      int node = node0 + nd;
      if (node >= n) continue;
      float den = 0.f, acc = 0.f;
      int hits = 0;
      for (int j = 0; j < cnt; j++) {
        int2 sd = binned_sd[s0 + j];
        if (sd.y == node) {           // wave-uniform branch
          float e = exf[(size_t)(s0 + j) * 4 + h];
          float v = hn[(size_t)sd.x * 64 + lane];
          den += e; acc += e * v; hits++;
        }
      }
      float r = (hits > 0) ? acc / den : 0.f;
      out[(size_t)node * 64 + lane] =
          r + bias[lane] + xin[(size_t)node * 64 + lane];
    }
  }
}

extern "C" void kernel_launch(void* const* d_in, const int* in_sizes, int n_in,
                              void* d_out, int out_size, void* d_ws, size_t ws_size,
                              hipStream_t stream) {
  const float* xn  = (const float*)d_in[0];
  const float* xe  = (const float*)d_in[1];
  const int*   src = (const int*)d_in[2];
  const int*   dst = (const int*)d_in[3];
  const float* Wn  = (const float*)d_in[4];
  const float* We  = (const float*)d_in[5];
  const float* aq  = (const float*)d_in[6];
  const float* ak  = (const float*)d_in[7];
  const float* ae  = (const float*)d_in[8];
  const float* bias = (const float*)d_in[9];
  float* out = (float*)d_out;

  const int n = in_sizes[0] / 64;   // 100000
  const int E = in_sizes[2];        // 1600000
  const int B = (n + NPB - 1) >> NPB_SHIFT;  // 6250 buckets

  // workspace carve (256B aligned)
  size_t off = 0;
  auto carve = [&](size_t bytes) {
    size_t p = off;
    off = (off + bytes + 255) & ~(size_t)255;
    return p;
  };
  char* ws = (char*)d_ws;
  size_t o_hn    = carve((size_t)n * 64 * 4);
  size_t o_wq    = carve((size_t)n * 4 * 4);
  size_t o_wk    = carve((size_t)n * 4 * 4);
  size_t o_qv    = carve(256 * 4);
  size_t o_kv    = carve(256 * 4);
  size_t o_ev    = carve(256 * 4);
  size_t o_bcnt  = carve((size_t)B * PAD * 4);
  size_t o_bcur  = carve((size_t)B * PAD * 4);
  size_t o_bst   = carve((size_t)(B + 1) * 4);
  size_t o_bsd   = carve((size_t)E * 8);
  size_t o_bex   = carve((size_t)E * 16);
  if (off > ws_size) return;  // insufficient workspace -> fail loudly

  float* hn      = (float*)(ws + o_hn);
  float* wq      = (float*)(ws + o_wq);
  float* wk      = (float*)(ws + o_wk);
  float* qv      = (float*)(ws + o_qv);
  float* kv      = (float*)(ws + o_kv);
  float* ev      = (float*)(ws + o_ev);
  int*   bcount  = (int*)(ws + o_bcnt);
  int*   bcur    = (int*)(ws + o_bcur);
  int*   bstart  = (int*)(ws + o_bst);
  int2*  binned_sd = (int2*)(ws + o_bsd);
  float4* binned_ex = (float4*)(ws + o_bex);

  zero_pad<<<(B * PAD + 1023) / 1024, 1024, 0, stream>>>(bcount, B * PAD);
  fold_kernel<<<1, 256, 0, stream>>>(Wn, We, aq, ak, ae, qv, kv, ev);
  node_proj<<<(n + 255) / 256, 256, 0, stream>>>(xn, Wn, aq, ak, hn, wq, wk, n);
  bhist<<<(E + 255) / 256, 256, 0, stream>>>(dst, bcount, E);
  bscan<<<1, 1024, 0, stream>>>(bcount, bstart, bcur, B, E);
  edge_scatter<<<(E + 255) / 256, 256, 0, stream>>>(
      xe, src, dst, ev, wq, wk, bcur, binned_sd, binned_ex, E);
  bucket_aggregate<<<B, 256, 0, stream>>>(
      bstart, binned_sd, binned_ex, hn, xn, bias, out, n);
}